// Round 5
// baseline (585.184 us; speedup 1.0000x reference)
//
#include <hip/hip_runtime.h>

constexpr int DEG   = 31;   // neighbors per node
constexpr int NEV   = 32;   // events per node (self + neighbors)
constexpr int TH    = 16;   // threshold: track dp[0..15] + absorbing "over"
constexpr int BLK   = 128;  // 15872 B LDS -> 10 blocks/CU

__global__ void zero_out_kernel(float* out) {
    if (threadIdx.x == 0) out[0] = 0.0f;
}

__device__ __forceinline__ float fast_sigmoid(float x) {
    return 1.0f / (1.0f + __expf(-x));
}

__global__ __launch_bounds__(BLK)
void pgl_kernel(const float* __restrict__ gains,
                const int*   __restrict__ nbr,
                float*       __restrict__ out,
                int n) {
    __shared__ int s_idx[BLK * DEG];          // 15872 B
    __shared__ float s_red[BLK / 64];

    const int tid        = threadIdx.x;
    const int blockStart = blockIdx.x * BLK;

    // ---- stage this block's neighbor rows into LDS, coalesced int4 ----
    const int rows  = min(BLK, n - blockStart);
    const int elems = rows * DEG;
    const int base  = blockStart * DEG;

    const int4* nb4 = (const int4*)(nbr + base);
    int4*       s4  = (int4*)s_idx;
    const int nvec  = elems >> 2;
    for (int v = tid; v < nvec; v += BLK) s4[v] = nb4[v];
    for (int e = (nvec << 2) + tid; e < elems; e += BLK) s_idx[e] = nbr[base + e];
    __syncthreads();

    float local = 0.0f;
    const int i = blockStart + tid;
    if (i < n) {
        const int* row = s_idx + tid * DEG;  // stride-31 LDS: 2-way alias only (free)

        // ---- all 32 values via nt (no-allocate / streaming) gathers ----
        // Experiment: if L1 line-fill occupancy is what throttles the TCP to
        // ~0.3 req/cy/CU, removing allocation should lift the service rate.
        float g[NEV];
        g[0] = __builtin_nontemporal_load(gains + i);
        #pragma unroll
        for (int j = 1; j < NEV; ++j)
            g[j] = __builtin_nontemporal_load(gains + row[j - 1]);

        // ---- sigmoids ----
        float pv[NEV];
        #pragma unroll
        for (int j = 0; j < NEV; ++j) pv[j] = fast_sigmoid(g[j]);

        // ---- absorbing-state Poisson-binomial DP ----
        float dp[TH];
        dp[0] = 1.0f;
        #pragma unroll
        for (int k = 1; k < TH; ++k) dp[k] = 0.0f;
        float over = 0.0f;

        #pragma unroll
        for (int j = 0; j < NEV; ++j) {
            const float pj = pv[j];
            if (j >= TH - 1) over = fmaf(dp[TH - 1], pj, over);
            const int kmax = (j + 1 < TH - 1) ? (j + 1) : (TH - 1);
            #pragma unroll
            for (int k = kmax; k >= 1; --k)
                dp[k] = fmaf(pj, dp[k - 1] - dp[k], dp[k]);
            dp[0] = fmaf(-pj, dp[0], dp[0]);
        }
        // contribution to -(loss): 0.25*p0 - P(count>=16)
        local = fmaf(0.25f, pv[0], -over);
    }

    // ---- block reduction: wave shuffle -> LDS -> one atomic per block ----
    #pragma unroll
    for (int off = 32; off > 0; off >>= 1)
        local += __shfl_down(local, off, 64);
    if ((tid & 63) == 0) s_red[tid >> 6] = local;
    __syncthreads();
    if (tid == 0) {
        float s = 0.0f;
        #pragma unroll
        for (int w = 0; w < BLK / 64; ++w) s += s_red[w];
        atomicAdd(out, s);
    }
}

extern "C" void kernel_launch(void* const* d_in, const int* in_sizes, int n_in,
                              void* d_out, int out_size, void* d_ws, size_t ws_size,
                              hipStream_t stream) {
    const float* gains = (const float*)d_in[0];
    const int*   nbr   = (const int*)d_in[1];
    float*       out   = (float*)d_out;
    const int n = in_sizes[0];

    zero_out_kernel<<<1, 64, 0, stream>>>(out);
    const int grid = (n + BLK - 1) / BLK;
    pgl_kernel<<<grid, BLK, 0, stream>>>(gains, nbr, out, n);
}

// Round 6
// 399.053 us; speedup vs baseline: 1.4664x; 1.4664x over previous
//
#include <hip/hip_runtime.h>
#include <hip/hip_fp16.h>

constexpr int DEG   = 31;       // neighbors per node
constexpr int TH    = 16;       // threshold: dp[0..15] + absorbing "over"
constexpr int BLK   = 1024;     // big blocks: staging traffic = (n/BLK) * table
constexpr int CHUNK = 65536;    // fp16 entries per LDS chunk = 128 KB
constexpr int NCHNK = 16;       // ceil(1e6 / 65536)
constexpr int TBL   = NCHNK * CHUNK;   // padded table entries

// ---------- small helpers ----------
__device__ __forceinline__ float fast_sigmoid(float x) {
    return 1.0f / (1.0f + __expf(-x));
}

__global__ void zero_out_kernel(float* out) {
    if (threadIdx.x == 0) out[0] = 0.0f;
}

// ---------- phase 1: p16[i] = (half)sigmoid(gains[i]), zero-padded ----------
__global__ __launch_bounds__(256)
void build_table_kernel(const float* __restrict__ gains,
                        __half* __restrict__ tbl, int n) {
    const int i = blockIdx.x * 256 + threadIdx.x;
    if (i < TBL) {
        float p = 0.0f;
        if (i < n) p = fast_sigmoid(gains[i]);
        tbl[i] = __float2half_rn(p);
    }
}

// ---------- phase 2: LDS multi-pass gather + DP ----------
__global__ __launch_bounds__(BLK)
void pgl_lds_kernel(const float* __restrict__ gains,
                    const int*   __restrict__ nbr,
                    const __half* __restrict__ tbl,
                    float*       __restrict__ out, int n) {
    __shared__ __align__(16) unsigned char lds_raw[CHUNK * 2];  // 128 KB, multi-use
    __shared__ float s_red[BLK / 64];

    const int tid        = threadIdx.x;
    const int blockStart = blockIdx.x * BLK;
    const int i          = blockStart + tid;

    // ---- stage this block's neighbor rows (coalesced int4), pull to VGPRs ----
    const int rows  = min(BLK, n - blockStart);
    const int elems = rows * DEG;               // <= 31744 ints = 127 KB, fits
    const int base  = blockStart * DEG;
    {
        const int4* nb4 = (const int4*)(nbr + base);
        int4*       s4  = (int4*)lds_raw;
        int*        s1  = (int*)lds_raw;
        const int nvec = elems >> 2;
        for (int v = tid; v < nvec; v += BLK) s4[v] = nb4[v];
        for (int e = (nvec << 2) + tid; e < elems; e += BLK) s1[e] = nbr[base + e];
    }
    __syncthreads();

    unsigned idx[DEG];
    if (i < n) {
        const int* sidx = (const int*)lds_raw;
        #pragma unroll
        for (int j = 0; j < DEG; ++j) idx[j] = (unsigned)sidx[tid * DEG + j];
    } else {
        #pragma unroll
        for (int j = 0; j < DEG; ++j) idx[j] = 0u;
    }
    __syncthreads();   // done with index staging; chunk loop reuses lds_raw

    // ---- stream the table through LDS; harvest this thread's 31 p-values ----
    __half pv[DEG];
    #pragma unroll
    for (int j = 0; j < DEG; ++j) pv[j] = __half(0.0f);

    const int4* tbl4 = (const int4*)tbl;        // 8 halfs per int4
    for (int c = 0; c < NCHNK; ++c) {
        int4* c4 = (int4*)lds_raw;
        const int cbase = c * (CHUNK / 8);
        #pragma unroll
        for (int t = 0; t < (CHUNK / 8) / BLK; ++t) {   // 8 x 16B per thread
            const int v = t * BLK + tid;
            c4[v] = tbl4[cbase + v];
        }
        __syncthreads();

        const __half* ch = (const __half*)lds_raw;
        #pragma unroll
        for (int j = 0; j < DEG; ++j) {
            if ((idx[j] >> 16) == (unsigned)c)          // exactly one c matches per j
                pv[j] = ch[idx[j] & 0xFFFFu];           // LDS random read: cheap
        }
        __syncthreads();
    }

    // ---- absorbing-state Poisson-binomial DP (unconditional, full lanes) ----
    float local = 0.0f;
    if (i < n) {
        float dp[TH];
        dp[0] = 1.0f;
        #pragma unroll
        for (int k = 1; k < TH; ++k) dp[k] = 0.0f;
        float over = 0.0f;

        const float p0 = fast_sigmoid(gains[i]);        // self stays fp32

        #pragma unroll
        for (int j = 0; j <= DEG; ++j) {
            const float pj = (j == 0) ? p0 : __half2float(pv[j - 1]);
            if (j >= TH - 1) over = fmaf(dp[TH - 1], pj, over);
            const int kmax = (j + 1 < TH - 1) ? (j + 1) : (TH - 1);
            #pragma unroll
            for (int k = kmax; k >= 1; --k)
                dp[k] = fmaf(pj, dp[k - 1] - dp[k], dp[k]);
            dp[0] = fmaf(-pj, dp[0], dp[0]);
        }
        local = fmaf(0.25f, p0, -over);                 // -(loss) contribution
    }

    // ---- block reduction: wave shuffle -> LDS -> one atomic per block ----
    #pragma unroll
    for (int o = 32; o > 0; o >>= 1) local += __shfl_down(local, o, 64);
    if ((tid & 63) == 0) s_red[tid >> 6] = local;
    __syncthreads();
    if (tid == 0) {
        float s = 0.0f;
        #pragma unroll
        for (int w = 0; w < BLK / 64; ++w) s += s_red[w];
        atomicAdd(out, s);
    }
}

// ---------- fallback (ws too small): round-1 direct-gather kernel ----------
constexpr int FBLK = 128;
__global__ __launch_bounds__(FBLK)
void pgl_direct_kernel(const float* __restrict__ gains,
                       const int*   __restrict__ nbr,
                       float*       __restrict__ out, int n) {
    __shared__ int s_idx[FBLK * DEG];
    __shared__ float s_red[FBLK / 64];
    const int tid = threadIdx.x;
    const int blockStart = blockIdx.x * FBLK;
    const int rows  = min(FBLK, n - blockStart);
    const int elems = rows * DEG;
    const int base  = blockStart * DEG;
    const int4* nb4 = (const int4*)(nbr + base);
    int4* s4 = (int4*)s_idx;
    const int nvec = elems >> 2;
    for (int v = tid; v < nvec; v += FBLK) s4[v] = nb4[v];
    for (int e = (nvec << 2) + tid; e < elems; e += FBLK) s_idx[e] = nbr[base + e];
    __syncthreads();
    float local = 0.0f;
    const int i = blockStart + tid;
    if (i < n) {
        const int* row = s_idx + tid * DEG;
        float dp[TH];
        dp[0] = 1.0f;
        #pragma unroll
        for (int k = 1; k < TH; ++k) dp[k] = 0.0f;
        float over = 0.0f;
        const float p0 = fast_sigmoid(gains[i]);
        #pragma unroll
        for (int j = 0; j <= DEG; ++j) {
            const float pj = (j == 0) ? p0 : fast_sigmoid(gains[row[j - 1]]);
            if (j >= TH - 1) over = fmaf(dp[TH - 1], pj, over);
            const int kmax = (j + 1 < TH - 1) ? (j + 1) : (TH - 1);
            #pragma unroll
            for (int k = kmax; k >= 1; --k)
                dp[k] = fmaf(pj, dp[k - 1] - dp[k], dp[k]);
            dp[0] = fmaf(-pj, dp[0], dp[0]);
        }
        local = fmaf(0.25f, p0, -over);
    }
    #pragma unroll
    for (int o = 32; o > 0; o >>= 1) local += __shfl_down(local, o, 64);
    if ((tid & 63) == 0) s_red[tid >> 6] = local;
    __syncthreads();
    if (tid == 0) {
        float s = 0.0f;
        #pragma unroll
        for (int w = 0; w < FBLK / 64; ++w) s += s_red[w];
        atomicAdd(out, s);
    }
}

extern "C" void kernel_launch(void* const* d_in, const int* in_sizes, int n_in,
                              void* d_out, int out_size, void* d_ws, size_t ws_size,
                              hipStream_t stream) {
    const float* gains = (const float*)d_in[0];
    const int*   nbr   = (const int*)d_in[1];
    float*       out   = (float*)d_out;
    const int n = in_sizes[0];

    zero_out_kernel<<<1, 64, 0, stream>>>(out);

    if (ws_size >= (size_t)TBL * sizeof(__half)) {
        __half* tbl = (__half*)d_ws;
        build_table_kernel<<<(TBL + 255) / 256, 256, 0, stream>>>(gains, tbl, n);
        const int grid = (n + BLK - 1) / BLK;
        pgl_lds_kernel<<<grid, BLK, 0, stream>>>(gains, nbr, tbl, out, n);
    } else {
        const int grid = (n + FBLK - 1) / FBLK;
        pgl_direct_kernel<<<grid, FBLK, 0, stream>>>(gains, nbr, out, n);
    }
}